// Round 1
// baseline (827.400 us; speedup 1.0000x reference)
//
#include <hip/hip_runtime.h>

typedef unsigned short u16;
using bf16x8 = __attribute__((ext_vector_type(8))) __bf16;
using f32x4  = __attribute__((ext_vector_type(4))) float;

__device__ __forceinline__ u16 f2bf(float f) {
    unsigned u = __builtin_bit_cast(unsigned, f);
    u += 0x7fffu + ((u >> 16) & 1u);
    return (u16)(u >> 16);
}
__device__ __forceinline__ float bf2f(u16 h) {
    unsigned u = ((unsigned)h) << 16;
    return __builtin_bit_cast(float, u);
}

__device__ __forceinline__ float wred_max(float v) {
    #pragma unroll
    for (int o = 32; o; o >>= 1) v = fmaxf(v, __shfl_xor(v, o, 64));
    return v;
}
__device__ __forceinline__ float wred_sum(float v) {
    #pragma unroll
    for (int o = 32; o; o >>= 1) v += __shfl_xor(v, o, 64);
    return v;
}

// ---------------------------------------------------------------- cast fp32->bf16
__global__ __launch_bounds__(256)
void cast_bf16(const float* __restrict__ src, u16* __restrict__ dst, int n4) {
    int i = blockIdx.x * 256 + threadIdx.x;
    if (i < n4) {
        float4 f = ((const float4*)src)[i];
        ushort4 u;
        u.x = f2bf(f.x); u.y = f2bf(f.y); u.z = f2bf(f.z); u.w = f2bf(f.w);
        ((ushort4*)dst)[i] = u;
    }
}

// ---------------------------------------------------------------- GEMM C = A * Bt^T
// A: [M,K] bf16 row-major.  Bt: [N,K] bf16 row-major (i.e. B transposed, K contiguous).
// 128x128 tile / block of 256 threads (4 waves, 2x2 of 64x64), BK=32, mfma 16x16x32.
// MODE 0: QKV projection epilogue. N=3072 logical cols: [Q | K | V]. Adds bias.
//         Q,K stored [m,1024] bf16; V stored transposed Vt[b][e][n] bf16.
// MODE 1: scale + bf16 store to oS [M,N].
// MODE 2: fp32 store to oF [M,N].
template<int MODE>
__global__ __launch_bounds__(256, 2)
void gemm_bt(const u16* __restrict__ A, const u16* __restrict__ Bt,
             const int M, const int N, const int K,
             u16* __restrict__ oQ, u16* __restrict__ oK, u16* __restrict__ oVt,
             const float* __restrict__ bQ, const float* __restrict__ bK,
             const float* __restrict__ bV,
             u16* __restrict__ oS, float* __restrict__ oF, const float scale)
{
    __shared__ u16 As[128 * 32];
    __shared__ u16 Bs[128 * 32];

    const int tid  = threadIdx.x;
    const int wv   = tid >> 6;
    const int lane = tid & 63;
    const int wr   = (wv >> 1) << 6;   // wave row offset: 0/64
    const int wc   = (wv & 1) << 6;    // wave col offset: 0/64

    const int row0 = blockIdx.y * 128;
    const int col0 = blockIdx.x * 128;

    // staging: each thread one 16B chunk in each of 2 row-halves of A and B tiles
    const int srow = tid >> 2;          // 0..63
    const int scol = (tid & 3) << 3;    // 0,8,16,24 (bf16 units)

    const u16* pA0 = A  + (size_t)(row0 + srow) * K + scol;
    const u16* pA1 = pA0 + (size_t)64 * K;
    const u16* pB0 = Bt + (size_t)(col0 + srow) * K + scol;
    const u16* pB1 = pB0 + (size_t)64 * K;

    u16* sA0 = &As[srow * 32 + scol];
    u16* sA1 = &As[(srow + 64) * 32 + scol];
    u16* sB0 = &Bs[srow * 32 + scol];
    u16* sB1 = &Bs[(srow + 64) * 32 + scol];

    const int fr = lane & 15;           // fragment row (m or n within 16-tile)
    const int kc = (lane >> 4) << 3;    // k chunk offset within 32

    f32x4 acc[4][4];
    #pragma unroll
    for (int i = 0; i < 4; i++)
        #pragma unroll
        for (int j = 0; j < 4; j++) acc[i][j] = (f32x4){0.f, 0.f, 0.f, 0.f};

    for (int k0 = 0; k0 < K; k0 += 32) {
        int4 a0 = *(const int4*)(pA0 + k0);
        int4 a1 = *(const int4*)(pA1 + k0);
        int4 b0 = *(const int4*)(pB0 + k0);
        int4 b1 = *(const int4*)(pB1 + k0);
        __syncthreads();
        *(int4*)sA0 = a0; *(int4*)sA1 = a1;
        *(int4*)sB0 = b0; *(int4*)sB1 = b1;
        __syncthreads();
        bf16x8 af[4], bfr[4];
        #pragma unroll
        for (int i = 0; i < 4; i++) af[i]  = *(const bf16x8*)&As[(wr + 16 * i + fr) * 32 + kc];
        #pragma unroll
        for (int j = 0; j < 4; j++) bfr[j] = *(const bf16x8*)&Bs[(wc + 16 * j + fr) * 32 + kc];
        #pragma unroll
        for (int i = 0; i < 4; i++)
            #pragma unroll
            for (int j = 0; j < 4; j++)
                acc[i][j] = __builtin_amdgcn_mfma_f32_16x16x32_bf16(af[i], bfr[j], acc[i][j], 0, 0, 0);
    }

    // epilogue: C/D layout col = lane&15, row = (lane>>4)*4 + reg
    const int rB = (lane >> 4) << 2;
    const int cB = lane & 15;

    if (MODE == 0) {
        const int sel = col0 >> 10;     // 0=Q 1=K 2=V (block never straddles)
        const float* bias = (sel == 0) ? bQ : (sel == 1 ? bK : bV);
        #pragma unroll
        for (int i = 0; i < 4; i++) {
            #pragma unroll
            for (int j = 0; j < 4; j++) {
                const int m0 = row0 + wr + 16 * i + rB;
                const int e  = (col0 & 1023) + wc + 16 * j + cB;
                const float bb = bias[e];
                if (sel < 2) {
                    u16* dst = (sel == 0) ? oQ : oK;
                    #pragma unroll
                    for (int t = 0; t < 4; t++)
                        dst[(size_t)(m0 + t) * 1024 + e] = f2bf(acc[i][j][t] + bb);
                } else {
                    const int b  = m0 >> 12;
                    const int n0 = m0 & 4095;
                    ushort4 pk;
                    pk.x = f2bf(acc[i][j][0] + bb);
                    pk.y = f2bf(acc[i][j][1] + bb);
                    pk.z = f2bf(acc[i][j][2] + bb);
                    pk.w = f2bf(acc[i][j][3] + bb);
                    *(ushort4*)&oVt[(size_t)b * 4194304 + (size_t)e * 4096 + n0] = pk;
                }
            }
        }
    } else if (MODE == 1) {
        #pragma unroll
        for (int i = 0; i < 4; i++)
            #pragma unroll
            for (int j = 0; j < 4; j++) {
                const int m0 = row0 + wr + 16 * i + rB;
                const int c  = col0 + wc + 16 * j + cB;
                #pragma unroll
                for (int t = 0; t < 4; t++)
                    oS[(size_t)(m0 + t) * N + c] = f2bf(acc[i][j][t] * scale);
            }
    } else {
        #pragma unroll
        for (int i = 0; i < 4; i++)
            #pragma unroll
            for (int j = 0; j < 4; j++) {
                const int m0 = row0 + wr + 16 * i + rB;
                const int c  = col0 + wc + 16 * j + cB;
                #pragma unroll
                for (int t = 0; t < 4; t++)
                    oF[(size_t)(m0 + t) * N + c] = acc[i][j][t];
            }
    }
}

// ---------------------------------------------------------------- row softmax (in place), row len 4096 bf16
__global__ __launch_bounds__(256)
void softmax_rows(u16* __restrict__ P) {
    const size_t row = blockIdx.x;
    u16* p = P + (row << 12);
    const int t = threadIdx.x;
    const int wv = t >> 6, lane = t & 63;

    u16 u[16];
    *(int4*)&u[0] = *(const int4*)(p + t * 16);
    *(int4*)&u[8] = *(const int4*)(p + t * 16 + 8);
    float v[16];
    #pragma unroll
    for (int i = 0; i < 16; i++) v[i] = bf2f(u[i]);

    float m = v[0];
    #pragma unroll
    for (int i = 1; i < 16; i++) m = fmaxf(m, v[i]);
    m = wred_max(m);
    __shared__ float sm[4];
    __shared__ float ss[4];
    if (lane == 0) sm[wv] = m;
    __syncthreads();
    m = fmaxf(fmaxf(sm[0], sm[1]), fmaxf(sm[2], sm[3]));

    float s = 0.f;
    #pragma unroll
    for (int i = 0; i < 16; i++) { v[i] = __expf(v[i] - m); s += v[i]; }
    s = wred_sum(s);
    if (lane == 0) ss[wv] = s;
    __syncthreads();
    s = ss[0] + ss[1] + ss[2] + ss[3];
    const float inv = 1.0f / s;

    #pragma unroll
    for (int i = 0; i < 16; i++) u[i] = f2bf(v[i] * inv);
    *(int4*)(p + t * 16)     = *(const int4*)&u[0];
    *(int4*)(p + t * 16 + 8) = *(const int4*)&u[8];
}

// ---------------------------------------------------------------- residual + LayerNorm (in place on out)
__global__ __launch_bounds__(256)
void residual_ln(const float* __restrict__ emb, float* __restrict__ out,
                 const float* __restrict__ gamma, const float* __restrict__ beta) {
    const size_t row = blockIdx.x;
    const int t = threadIdx.x;
    const int wv = t >> 6, lane = t & 63;
    const size_t base = row * 1024 + t * 4;

    float4 ev = *(const float4*)(emb + base);
    float4 ov = *(const float4*)(out + base);
    float x0 = ev.x + ov.x, x1 = ev.y + ov.y, x2 = ev.z + ov.z, x3 = ev.w + ov.w;

    float s = x0 + x1 + x2 + x3;
    float q = x0 * x0 + x1 * x1 + x2 * x2 + x3 * x3;
    s = wred_sum(s);
    q = wred_sum(q);
    __shared__ float s1[4], s2[4];
    if (lane == 0) { s1[wv] = s; s2[wv] = q; }
    __syncthreads();
    s = s1[0] + s1[1] + s1[2] + s1[3];
    q = s2[0] + s2[1] + s2[2] + s2[3];

    const float mu  = s * (1.0f / 1024.0f);
    const float var = q * (1.0f / 1024.0f) - mu * mu;
    const float r   = rsqrtf(var + 1e-5f);

    float4 g  = *(const float4*)(gamma + t * 4);
    float4 be = *(const float4*)(beta + t * 4);
    float4 res;
    res.x = (x0 - mu) * r * g.x + be.x;
    res.y = (x1 - mu) * r * g.y + be.y;
    res.z = (x2 - mu) * r * g.z + be.z;
    res.w = (x3 - mu) * r * g.w + be.w;
    *(float4*)(out + base) = res;
}

// ---------------------------------------------------------------- launch
extern "C" void kernel_launch(void* const* d_in, const int* in_sizes, int n_in,
                              void* d_out, int out_size, void* d_ws, size_t ws_size,
                              hipStream_t stream) {
    const float* emb   = (const float*)d_in[0];
    const float* Wq    = (const float*)d_in[4];
    const float* bq    = (const float*)d_in[5];
    const float* Wk    = (const float*)d_in[6];
    const float* bk    = (const float*)d_in[7];
    const float* Wv    = (const float*)d_in[8];
    const float* bv    = (const float*)d_in[9];
    const float* gamma = (const float*)d_in[10];
    const float* beta  = (const float*)d_in[11];
    float* out = (float*)d_out;

    char* ws = (char*)d_ws;
    // layout (bytes):
    //   [0,          33554432)  Xbf bf16 [16384,1024]  -- later reused as P [4096,4096] bf16
    //   [33554432,   39845888)  Wbf bf16 [3072,1024]   (Wq|Wk|Wv rows)
    //   [39845888,   73400320)  Qbf bf16 [16384,1024]
    //   [73400320,  106954752)  Kbf bf16 [16384,1024]
    //   [106954752, 140509184)  Vt  bf16 [4][1024][4096]
    if (ws_size < 140509184u) return;
    u16* Xbf = (u16*)(ws);
    u16* Wbf = (u16*)(ws + 33554432);
    u16* Qbf = (u16*)(ws + 39845888);
    u16* Kbf = (u16*)(ws + 73400320);
    u16* Vt  = (u16*)(ws + 106954752);

    cast_bf16<<<16384, 256, 0, stream>>>(emb, Xbf, 4194304);
    cast_bf16<<<1024, 256, 0, stream>>>(Wq, Wbf,           262144);
    cast_bf16<<<1024, 256, 0, stream>>>(Wk, Wbf + 1048576, 262144);
    cast_bf16<<<1024, 256, 0, stream>>>(Wv, Wbf + 2097152, 262144);

    // fused QKV projection: [16384,3072] = Xbf @ Wbf^T + bias
    gemm_bt<0><<<dim3(24, 128), 256, 0, stream>>>(Xbf, Wbf, 16384, 3072, 1024,
        Qbf, Kbf, Vt, bq, bk, bv, nullptr, nullptr, 1.0f);

    u16* P = Xbf;  // reuse
    for (int b = 0; b < 4; ++b) {
        const size_t o = (size_t)b * 4194304;  // 4096*1024
        // S = (Q K^T) / 32  -> bf16 [4096,4096]
        gemm_bt<1><<<dim3(32, 32), 256, 0, stream>>>(Qbf + o, Kbf + o, 4096, 4096, 1024,
            nullptr, nullptr, nullptr, nullptr, nullptr, nullptr, P, nullptr, 0.03125f);
        softmax_rows<<<4096, 256, 0, stream>>>(P);
        // O = P @ V  (Bt = Vt[b], [1024,4096]) -> fp32 to d_out
        gemm_bt<2><<<dim3(8, 32), 256, 0, stream>>>(P, Vt + o, 4096, 1024, 4096,
            nullptr, nullptr, nullptr, nullptr, nullptr, nullptr, nullptr, out + o, 1.0f);
    }

    residual_ln<<<16384, 256, 0, stream>>>(emb, out, gamma, beta);
}

// Round 2
// 770.834 us; speedup vs baseline: 1.0734x; 1.0734x over previous
//
#include <hip/hip_runtime.h>

typedef unsigned short u16;
using bf16x8 = __attribute__((ext_vector_type(8))) __bf16;
using f32x4  = __attribute__((ext_vector_type(4))) float;

__device__ __forceinline__ u16 f2bf(float f) {
    unsigned u = __builtin_bit_cast(unsigned, f);
    u += 0x7fffu + ((u >> 16) & 1u);
    return (u16)(u >> 16);
}
__device__ __forceinline__ float bf2f(u16 h) {
    unsigned u = ((unsigned)h) << 16;
    return __builtin_bit_cast(float, u);
}

__device__ __forceinline__ float wred_max(float v) {
    #pragma unroll
    for (int o = 32; o; o >>= 1) v = fmaxf(v, __shfl_xor(v, o, 64));
    return v;
}
__device__ __forceinline__ float wred_sum(float v) {
    #pragma unroll
    for (int o = 32; o; o >>= 1) v += __shfl_xor(v, o, 64);
    return v;
}

// async global->LDS, 16B per lane. LDS dest must be wave-uniform base + lane*16.
__device__ __forceinline__ void gl2lds16(const u16* g, void* l) {
    __builtin_amdgcn_global_load_lds(
        (__attribute__((address_space(1))) void*)(g),
        (__attribute__((address_space(3))) void*)(l), 16, 0, 0);
}

// ---------------------------------------------------------------- cast fp32->bf16
__global__ __launch_bounds__(256)
void cast_bf16(const float* __restrict__ src, u16* __restrict__ dst, int n4) {
    int i = blockIdx.x * 256 + threadIdx.x;
    if (i < n4) {
        float4 f = ((const float4*)src)[i];
        ushort4 u;
        u.x = f2bf(f.x); u.y = f2bf(f.y); u.z = f2bf(f.z); u.w = f2bf(f.w);
        ((ushort4*)dst)[i] = u;
    }
}

// ---------------------------------------------------------------- GEMM C = A * Bt^T
// A: [M,K] bf16 row-major.  Bt: [N,K] bf16 row-major (K contiguous).
// Tile TM x 128, 256 threads (4 waves, 2x2), BK=32, mfma 16x16x32, direct-to-LDS staging.
// MODE 0: QKV projection epilogue (bias; Q,K row-major; V transposed to Vt[b][e][n]).
// MODE 1: scale + bf16 store to oS.   MODE 2: fp32 store to oF.
template<int MODE, int TM>
__global__ __launch_bounds__(256, 2)
void gemm_bt(const u16* __restrict__ A, const u16* __restrict__ Bt,
             const int M, const int N, const int K,
             u16* __restrict__ oQ, u16* __restrict__ oK, u16* __restrict__ oVt,
             const float* __restrict__ bQ, const float* __restrict__ bK,
             const float* __restrict__ bV,
             u16* __restrict__ oS, float* __restrict__ oF, const float scale)
{
    __shared__ u16 As[TM * 32];
    __shared__ u16 Bs[128 * 32];

    constexpr int IM = TM / 32;         // per-wave m-tiles of 16
    const int tid  = threadIdx.x;
    const int wv   = tid >> 6;
    const int lane = tid & 63;
    const int wr   = (wv >> 1) * (TM / 2);
    const int wc   = (wv & 1) << 6;

    const int row0 = blockIdx.y * TM;
    const int col0 = blockIdx.x * 128;

    // staging: thread tid covers 16B chunk tid of each 64-row half-tile
    const int srow = tid >> 2;          // 0..63
    const int scol = (tid & 3) << 3;    // 0,8,16,24 (bf16 units)

    const u16* pA0 = A  + (size_t)(row0 + srow) * K + scol;
    const u16* pB0 = Bt + (size_t)(col0 + srow) * K + scol;

    // wave-uniform LDS bases (lane*16 is appended by HW)
    char* aB0 = (char*)As + wv * 1024;
    char* aB1 = (char*)As + 4096 + wv * 1024;
    char* bB0 = (char*)Bs + wv * 1024;
    char* bB1 = (char*)Bs + 4096 + wv * 1024;

    const int fr = lane & 15;
    const int kc = (lane >> 4) << 3;

    f32x4 acc[IM][4];
    #pragma unroll
    for (int i = 0; i < IM; i++)
        #pragma unroll
        for (int j = 0; j < 4; j++) acc[i][j] = (f32x4){0.f, 0.f, 0.f, 0.f};

    for (int k0 = 0; k0 < K; k0 += 32) {
        __syncthreads();
        gl2lds16(pA0 + k0, aB0);
        if (TM == 128) gl2lds16(pA0 + (size_t)64 * K + k0, aB1);
        gl2lds16(pB0 + k0, bB0);
        gl2lds16(pB0 + (size_t)64 * K + k0, bB1);
        __syncthreads();

        bf16x8 af[IM], bfr[4];
        #pragma unroll
        for (int i = 0; i < IM; i++) af[i]  = *(const bf16x8*)&As[(wr + 16 * i + fr) * 32 + kc];
        #pragma unroll
        for (int j = 0; j < 4; j++)  bfr[j] = *(const bf16x8*)&Bs[(wc + 16 * j + fr) * 32 + kc];
        #pragma unroll
        for (int i = 0; i < IM; i++)
            #pragma unroll
            for (int j = 0; j < 4; j++)
                acc[i][j] = __builtin_amdgcn_mfma_f32_16x16x32_bf16(af[i], bfr[j], acc[i][j], 0, 0, 0);
    }

    // epilogue: C/D layout col = lane&15, row = (lane>>4)*4 + reg
    const int rB = (lane >> 4) << 2;
    const int cB = lane & 15;

    if (MODE == 0) {
        const int sel = col0 >> 10;     // 0=Q 1=K 2=V (blocks never straddle)
        const float* bias = (sel == 0) ? bQ : (sel == 1 ? bK : bV);
        #pragma unroll
        for (int i = 0; i < IM; i++) {
            #pragma unroll
            for (int j = 0; j < 4; j++) {
                const int m0 = row0 + wr + 16 * i + rB;
                const int e  = (col0 & 1023) + wc + 16 * j + cB;
                const float bb = bias[e];
                if (sel < 2) {
                    u16* dst = (sel == 0) ? oQ : oK;
                    #pragma unroll
                    for (int t = 0; t < 4; t++)
                        dst[(size_t)(m0 + t) * 1024 + e] = f2bf(acc[i][j][t] + bb);
                } else {
                    const int b  = m0 >> 12;
                    const int n0 = m0 & 4095;
                    ushort4 pk;
                    pk.x = f2bf(acc[i][j][0] + bb);
                    pk.y = f2bf(acc[i][j][1] + bb);
                    pk.z = f2bf(acc[i][j][2] + bb);
                    pk.w = f2bf(acc[i][j][3] + bb);
                    *(ushort4*)&oVt[(size_t)b * 4194304 + (size_t)e * 4096 + n0] = pk;
                }
            }
        }
    } else if (MODE == 1) {
        #pragma unroll
        for (int i = 0; i < IM; i++)
            #pragma unroll
            for (int j = 0; j < 4; j++) {
                const int m0 = row0 + wr + 16 * i + rB;
                const int c  = col0 + wc + 16 * j + cB;
                #pragma unroll
                for (int t = 0; t < 4; t++)
                    oS[(size_t)(m0 + t) * N + c] = f2bf(acc[i][j][t] * scale);
            }
    } else {
        #pragma unroll
        for (int i = 0; i < IM; i++)
            #pragma unroll
            for (int j = 0; j < 4; j++) {
                const int m0 = row0 + wr + 16 * i + rB;
                const int c  = col0 + wc + 16 * j + cB;
                #pragma unroll
                for (int t = 0; t < 4; t++)
                    oF[(size_t)(m0 + t) * N + c] = acc[i][j][t];
            }
    }
}

// ---------------------------------------------------------------- row softmax (in place), row len 4096 bf16
__global__ __launch_bounds__(256)
void softmax_rows(u16* __restrict__ P) {
    const size_t row = blockIdx.x;
    u16* p = P + (row << 12);
    const int t = threadIdx.x;
    const int wv = t >> 6, lane = t & 63;

    u16 u[16];
    *(int4*)&u[0] = *(const int4*)(p + t * 16);
    *(int4*)&u[8] = *(const int4*)(p + t * 16 + 8);
    float v[16];
    #pragma unroll
    for (int i = 0; i < 16; i++) v[i] = bf2f(u[i]);

    float m = v[0];
    #pragma unroll
    for (int i = 1; i < 16; i++) m = fmaxf(m, v[i]);
    m = wred_max(m);
    __shared__ float sm[4];
    __shared__ float ss[4];
    if (lane == 0) sm[wv] = m;
    __syncthreads();
    m = fmaxf(fmaxf(sm[0], sm[1]), fmaxf(sm[2], sm[3]));

    float s = 0.f;
    #pragma unroll
    for (int i = 0; i < 16; i++) { v[i] = __expf(v[i] - m); s += v[i]; }
    s = wred_sum(s);
    if (lane == 0) ss[wv] = s;
    __syncthreads();
    s = ss[0] + ss[1] + ss[2] + ss[3];
    const float inv = 1.0f / s;

    #pragma unroll
    for (int i = 0; i < 16; i++) u[i] = f2bf(v[i] * inv);
    *(int4*)(p + t * 16)     = *(const int4*)&u[0];
    *(int4*)(p + t * 16 + 8) = *(const int4*)&u[8];
}

// ---------------------------------------------------------------- residual + LayerNorm (in place on out)
__global__ __launch_bounds__(256)
void residual_ln(const float* __restrict__ emb, float* __restrict__ out,
                 const float* __restrict__ gamma, const float* __restrict__ beta) {
    const size_t row = blockIdx.x;
    const int t = threadIdx.x;
    const int wv = t >> 6, lane = t & 63;
    const size_t base = row * 1024 + t * 4;

    float4 ev = *(const float4*)(emb + base);
    float4 ov = *(const float4*)(out + base);
    float x0 = ev.x + ov.x, x1 = ev.y + ov.y, x2 = ev.z + ov.z, x3 = ev.w + ov.w;

    float s = x0 + x1 + x2 + x3;
    float q = x0 * x0 + x1 * x1 + x2 * x2 + x3 * x3;
    s = wred_sum(s);
    q = wred_sum(q);
    __shared__ float s1[4], s2[4];
    if (lane == 0) { s1[wv] = s; s2[wv] = q; }
    __syncthreads();
    s = s1[0] + s1[1] + s1[2] + s1[3];
    q = s2[0] + s2[1] + s2[2] + s2[3];

    const float mu  = s * (1.0f / 1024.0f);
    const float var = q * (1.0f / 1024.0f) - mu * mu;
    const float r   = rsqrtf(var + 1e-5f);

    float4 g  = *(const float4*)(gamma + t * 4);
    float4 be = *(const float4*)(beta + t * 4);
    float4 res;
    res.x = (x0 - mu) * r * g.x + be.x;
    res.y = (x1 - mu) * r * g.y + be.y;
    res.z = (x2 - mu) * r * g.z + be.z;
    res.w = (x3 - mu) * r * g.w + be.w;
    *(float4*)(out + base) = res;
}

// ---------------------------------------------------------------- launch
extern "C" void kernel_launch(void* const* d_in, const int* in_sizes, int n_in,
                              void* d_out, int out_size, void* d_ws, size_t ws_size,
                              hipStream_t stream) {
    const float* emb   = (const float*)d_in[0];
    const float* Wq    = (const float*)d_in[4];
    const float* bq    = (const float*)d_in[5];
    const float* Wk    = (const float*)d_in[6];
    const float* bk    = (const float*)d_in[7];
    const float* Wv    = (const float*)d_in[8];
    const float* bv    = (const float*)d_in[9];
    const float* gamma = (const float*)d_in[10];
    const float* beta  = (const float*)d_in[11];
    float* out = (float*)d_out;

    char* ws = (char*)d_ws;
    // layout (bytes):
    //   [0,          33554432)  Xbf bf16 [16384,1024]  -- later reused as P [4096,4096] bf16
    //   [33554432,   39845888)  Wbf bf16 [3072,1024]   (Wq|Wk|Wv rows)
    //   [39845888,   73400320)  Qbf bf16 [16384,1024]
    //   [73400320,  106954752)  Kbf bf16 [16384,1024]
    //   [106954752, 140509184)  Vt  bf16 [4][1024][4096]
    if (ws_size < 140509184u) return;
    u16* Xbf = (u16*)(ws);
    u16* Wbf = (u16*)(ws + 33554432);
    u16* Qbf = (u16*)(ws + 39845888);
    u16* Kbf = (u16*)(ws + 73400320);
    u16* Vt  = (u16*)(ws + 106954752);

    cast_bf16<<<16384, 256, 0, stream>>>(emb, Xbf, 4194304);
    cast_bf16<<<1024, 256, 0, stream>>>(Wq, Wbf,           262144);
    cast_bf16<<<1024, 256, 0, stream>>>(Wk, Wbf + 1048576, 262144);
    cast_bf16<<<1024, 256, 0, stream>>>(Wv, Wbf + 2097152, 262144);

    // fused QKV projection: [16384,3072] = Xbf @ Wbf^T + bias
    gemm_bt<0, 128><<<dim3(24, 128), 256, 0, stream>>>(Xbf, Wbf, 16384, 3072, 1024,
        Qbf, Kbf, Vt, bq, bk, bv, nullptr, nullptr, 1.0f);

    u16* P = Xbf;  // reuse
    for (int b = 0; b < 4; ++b) {
        const size_t o = (size_t)b * 4194304;  // 4096*1024
        // S = (Q K^T) / 32  -> bf16 [4096,4096]
        gemm_bt<1, 128><<<dim3(32, 32), 256, 0, stream>>>(Qbf + o, Kbf + o, 4096, 4096, 1024,
            nullptr, nullptr, nullptr, nullptr, nullptr, nullptr, P, nullptr, 0.03125f);
        softmax_rows<<<4096, 256, 0, stream>>>(P);
        // O = P @ V  (Bt = Vt[b], [1024,4096]) -> fp32 to d_out, 64-row tiles for 512 blocks
        gemm_bt<2, 64><<<dim3(8, 64), 256, 0, stream>>>(P, Vt + o, 4096, 1024, 4096,
            nullptr, nullptr, nullptr, nullptr, nullptr, nullptr, nullptr, out + o, 1.0f);
    }

    residual_ln<<<16384, 256, 0, stream>>>(emb, out, gamma, beta);
}